// Round 1
// baseline (208.116 us; speedup 1.0000x reference)
//
#include <hip/hip_runtime.h>
#include <hip/hip_bf16.h>
#include <stdint.h>

// B=4096, H=256, K=16, D=512 (8*64)
#define NB   4096
#define NH   256
#define NK   16
#define ND   512

using short8  = __attribute__((ext_vector_type(8))) short;
using float4v = __attribute__((ext_vector_type(4))) float;

__device__ __forceinline__ float fast_tanh(float x) {
  // tanh(x) = 1 - 2/(exp2(2x*log2e)+1); exp2/rcp are ~1ulp, fine vs bf16 budget
  float e = __builtin_amdgcn_exp2f(x * 2.88539008177793f);
  return 1.0f - 2.0f * __builtin_amdgcn_rcpf(e + 1.0f);
}

__device__ __forceinline__ unsigned short f2bf(float f) {
  union { float f; unsigned u; } v; v.f = f;
  unsigned r = v.u + 0x7FFF + ((v.u >> 16) & 1);  // RNE, inputs finite
  return (unsigned short)(r >> 16);
}

__device__ __forceinline__ float bf2f(unsigned short h) {
  union { unsigned u; float f; } v; v.u = ((unsigned)h) << 16; return v.f;
}

// ---------------------------------------------------------------- gating ----
// gates[b][k] = softmax_k( tanh(h_prev@gw1 + gb1) @ gw2 + gb2 )
// 8 rows per block so gw1 (256KB) is read 512x not 4096x.
__global__ __launch_bounds__(256) void k_gates(
    const float* __restrict__ h_prev, const float* __restrict__ gw1,
    const float* __restrict__ gb1, const float* __restrict__ gw2,
    const float* __restrict__ gb2, float* __restrict__ gates) {
  __shared__ float sh_h[8][256];
  __shared__ float sh_t[256][8];
  const int t = threadIdx.x;
  const int b0 = blockIdx.x * 8;
  for (int r = 0; r < 8; ++r) sh_h[r][t] = h_prev[(b0 + r) * NH + t];
  __syncthreads();
  float acc[8];
  float bias = gb1[t];
#pragma unroll
  for (int r = 0; r < 8; ++r) acc[r] = bias;
  for (int i = 0; i < NH; i += 4) {
    float w0 = gw1[(i + 0) * NH + t];
    float w1 = gw1[(i + 1) * NH + t];
    float w2 = gw1[(i + 2) * NH + t];
    float w3 = gw1[(i + 3) * NH + t];
#pragma unroll
    for (int r = 0; r < 8; ++r) {
      float4 hv = *(const float4*)&sh_h[r][i];
      acc[r] += hv.x * w0 + hv.y * w1 + hv.z * w2 + hv.w * w3;
    }
  }
#pragma unroll
  for (int r = 0; r < 8; ++r) sh_t[t][r] = fast_tanh(acc[r]);
  __syncthreads();
  if (t < 128) {
    const int r = t >> 4, k = t & 15;
    float lg = gb2[k];
    for (int j = 0; j < NH; ++j) lg += sh_t[j][r] * gw2[j * NK + k];
    float m = lg;
    for (int off = 1; off < 16; off <<= 1) m = fmaxf(m, __shfl_xor(m, off, 16));
    float e = __builtin_amdgcn_exp2f((lg - m) * 1.44269504f);
    float s = e;
    for (int off = 1; off < 16; off <<= 1) s += __shfl_xor(s, off, 16);
    gates[(b0 + r) * NK + k] = e * __builtin_amdgcn_rcpf(s);
  }
}

// --------------------------------------------------------------- h1 prep ----
// h1bf[k][b][d] = bf16( tanh(x_ext[b][k]*w1[k][d] + b1[k][d]) )
__global__ __launch_bounds__(256) void k_h1(
    const float* __restrict__ x_ext, const float* __restrict__ w1,
    const float* __restrict__ b1, unsigned short* __restrict__ h1bf) {
  const int gid = blockIdx.x * 256 + threadIdx.x;  // NB*NK*ND/8 threads
  const int d0 = (gid & 63) * 8;
  const int tmp = gid >> 6;       // k*NB + b
  const int b = tmp & (NB - 1);
  const int k = tmp >> 12;
  const float x = x_ext[b * NK + k];
  const float4 wlo = *(const float4*)&w1[k * ND + d0];
  const float4 whi = *(const float4*)&w1[k * ND + d0 + 4];
  const float4 blo = *(const float4*)&b1[k * ND + d0];
  const float4 bhi = *(const float4*)&b1[k * ND + d0 + 4];
  unsigned short o[8];
  o[0] = f2bf(fast_tanh(x * wlo.x + blo.x));
  o[1] = f2bf(fast_tanh(x * wlo.y + blo.y));
  o[2] = f2bf(fast_tanh(x * wlo.z + blo.z));
  o[3] = f2bf(fast_tanh(x * wlo.w + blo.w));
  o[4] = f2bf(fast_tanh(x * whi.x + bhi.x));
  o[5] = f2bf(fast_tanh(x * whi.y + bhi.y));
  o[6] = f2bf(fast_tanh(x * whi.z + bhi.z));
  o[7] = f2bf(fast_tanh(x * whi.w + bhi.w));
  *(uint4*)&h1bf[(size_t)tmp * ND + d0] = *(uint4*)o;
}

// ---------------------------------------------------------- w2 transpose ----
// w2t[k][e][d] = bf16( w2[k][d][e] )  -- so GEMM B-fragments are contiguous
__global__ __launch_bounds__(256) void k_w2t(
    const float* __restrict__ w2, unsigned short* __restrict__ w2t) {
  __shared__ float sh[64][65];
  const int t = threadIdx.x;
  const int e0 = blockIdx.x * 64;
  const int d0 = blockIdx.y * 64;
  const int k = blockIdx.z;
  const float* src = w2 + ((size_t)k * ND + d0) * ND + e0;
#pragma unroll
  for (int rep = 0; rep < 4; ++rep) {
    int r = rep * 16 + (t >> 4);
    int c = (t & 15) * 4;
    float4 v = *(const float4*)&src[(size_t)r * ND + c];
    sh[r][c] = v.x; sh[r][c + 1] = v.y; sh[r][c + 2] = v.z; sh[r][c + 3] = v.w;
  }
  __syncthreads();
  unsigned short* dst = w2t + ((size_t)k * ND + e0) * ND + d0;
#pragma unroll
  for (int rep = 0; rep < 2; ++rep) {
    int er = rep * 32 + (t >> 3);
    int dc = (t & 7) * 8;
    unsigned short o[8];
#pragma unroll
    for (int j = 0; j < 8; ++j) o[j] = f2bf(sh[dc + j][er]);
    *(uint4*)&dst[(size_t)er * ND + dc] = *(uint4*)o;
  }
}

// ------------------------------------------------------------------ GEMM ----
// per expert: h2bf[k][b][e] = bf16( tanh( h1[k][b][:] @ w2[k][:][e] + b2[k][e] ) )
// m97 recipe: 128x128 tile, BK=32, global_load_lds(16B), 16x16x32 bf16 MFMA.
__global__ __launch_bounds__(256) void k_gemm(
    const unsigned short* __restrict__ h1bf,  // [K][B][512]
    const unsigned short* __restrict__ w2t,   // [K][512e][512d]
    const float* __restrict__ b2,             // [K][512]
    unsigned short* __restrict__ h2bf) {      // [K][B][512]
  __shared__ __align__(16) unsigned short As[128 * 32];
  __shared__ __align__(16) unsigned short Bs[128 * 32];
  const int t = threadIdx.x;
  const int l = t & 63;
  const int w = t >> 6;
  const int n0 = blockIdx.x * 128;
  const int m0 = blockIdx.y * 128;
  const int ke = blockIdx.z;

  const char* Ab = (const char*)(h1bf + ((size_t)ke * NB + m0) * ND);
  const char* Bb = (const char*)(w2t + ((size_t)ke * ND + n0) * ND);

  const int wm = w & 1, wn = w >> 1;
  const int q = l >> 4, m16 = l & 15;

  float4v acc[4][4];
#pragma unroll
  for (int a = 0; a < 4; ++a)
#pragma unroll
    for (int b = 0; b < 4; ++b) acc[a][b] = (float4v){0.f, 0.f, 0.f, 0.f};

  const int rowInC = l >> 2;        // 0..15 within 16-row chunk
  const int colByte = (l & 3) * 16; // 0..48 within 64B row

  for (int kk = 0; kk < 16; ++kk) {
    const int kof = kk * 64;  // byte offset into 1024B rows
#pragma unroll
    for (int j = 0; j < 2; ++j) {
      int c = w * 2 + j;                 // chunk 0..7 (wave-uniform)
      int r = c * 16 + rowInC;           // tile row 0..127
      __builtin_amdgcn_global_load_lds(
          (const __attribute__((address_space(1))) void*)(Ab + (size_t)r * 1024 + kof + colByte),
          (__attribute__((address_space(3))) void*)&As[c * 512], 16, 0, 0);
      __builtin_amdgcn_global_load_lds(
          (const __attribute__((address_space(1))) void*)(Bb + (size_t)r * 1024 + kof + colByte),
          (__attribute__((address_space(3))) void*)&Bs[c * 512], 16, 0, 0);
    }
    __syncthreads();  // drains vmcnt before barrier
    short8 af[4], bfm[4];
#pragma unroll
    for (int i = 0; i < 4; ++i)
      af[i] = *(const short8*)&As[(wm * 64 + i * 16 + m16) * 32 + q * 8];
#pragma unroll
    for (int i = 0; i < 4; ++i)
      bfm[i] = *(const short8*)&Bs[(wn * 64 + i * 16 + m16) * 32 + q * 8];
#pragma unroll
    for (int a = 0; a < 4; ++a)
#pragma unroll
      for (int b = 0; b < 4; ++b)
        acc[a][b] = __builtin_amdgcn_mfma_f32_16x16x32_bf16(af[a], bfm[b], acc[a][b], 0, 0, 0);
    __syncthreads();
  }

  // epilogue: +b2, tanh, bf16 store. C/D layout: col=lane&15, row=q*4+reg.
  const float* b2k = b2 + ke * ND;
  unsigned short* Ob = h2bf + (size_t)ke * NB * ND;
#pragma unroll
  for (int bni = 0; bni < 4; ++bni) {
    int col = n0 + wn * 64 + bni * 16 + m16;
    float bias = b2k[col];
#pragma unroll
    for (int ami = 0; ami < 4; ++ami) {
      int rbase = m0 + wm * 64 + ami * 16 + q * 4;
#pragma unroll
      for (int rr = 0; rr < 4; ++rr) {
        float vv = fast_tanh(acc[ami][bni][rr] + bias);
        Ob[(size_t)(rbase + rr) * ND + col] = f2bf(vv);
      }
    }
  }
}

// -------------------------------------------------- LN + gate-mix + final ----
// wave per b-row: stats over 512, theta = sum_k gate*LN(h2) + theta0, x_prime.
__global__ __launch_bounds__(256) void k_final(
    const unsigned short* __restrict__ h2bf,  // [K][B][512]
    const float* __restrict__ gates,          // [B][16]
    const float* __restrict__ x_l,            // [B][8]
    const float* __restrict__ ln_g, const float* __restrict__ ln_b,
    const float* __restrict__ theta0,         // [512]
    float* __restrict__ out) {
  const int t = threadIdx.x;
  const int l = t & 63;
  const int b = blockIdx.x * 4 + (t >> 6);
  const int d0 = l * 8;
  float g[8], bb[8], t0[8], acc[8];
  *(float4*)&g[0] = *(const float4*)&ln_g[d0];
  *(float4*)&g[4] = *(const float4*)&ln_g[d0 + 4];
  *(float4*)&bb[0] = *(const float4*)&ln_b[d0];
  *(float4*)&bb[4] = *(const float4*)&ln_b[d0 + 4];
  *(float4*)&t0[0] = *(const float4*)&theta0[d0];
  *(float4*)&t0[4] = *(const float4*)&theta0[d0 + 4];
#pragma unroll
  for (int j = 0; j < 8; ++j) acc[j] = 0.f;
  const float xl = x_l[b * 8 + (l >> 3)];

  for (int k = 0; k < NK; ++k) {
    uint4 raw = *(const uint4*)&h2bf[((size_t)k * NB + b) * ND + d0];
    const unsigned short* hp = (const unsigned short*)&raw;
    float v[8];
#pragma unroll
    for (int j = 0; j < 8; ++j) v[j] = bf2f(hp[j]);
    float s = 0.f, s2 = 0.f;
#pragma unroll
    for (int j = 0; j < 8; ++j) { s += v[j]; s2 += v[j] * v[j]; }
    for (int off = 1; off < 64; off <<= 1) {
      s += __shfl_xor(s, off, 64);
      s2 += __shfl_xor(s2, off, 64);
    }
    float mu = s * (1.f / 512.f);
    float var = s2 * (1.f / 512.f) - mu * mu;
    float rs = __builtin_amdgcn_rsqf(var + 1e-5f);
    float gate = gates[b * NK + k];
#pragma unroll
    for (int j = 0; j < 8; ++j) acc[j] += gate * ((v[j] - mu) * rs * g[j] + bb[j]);
  }
  float th[8];
#pragma unroll
  for (int j = 0; j < 8; ++j) th[j] = acc[j] + t0[j];
  float* thp = out + (size_t)NB * 64 + (size_t)b * ND + d0;
  *(float4*)&thp[0] = *(float4*)&th[0];
  *(float4*)&thp[4] = *(float4*)&th[4];
  // x_prime[b][e] = sum_i x_l[b][i]*theta[b][i][e]; lane l holds i=l>>3, e=(l&7)*8+j
  float p[8];
#pragma unroll
  for (int j = 0; j < 8; ++j) p[j] = xl * th[j];
  for (int off = 8; off < 64; off <<= 1)
#pragma unroll
    for (int j = 0; j < 8; ++j) p[j] += __shfl_xor(p[j], off, 64);
  if (l < 8) {
    float* xp = out + (size_t)b * 64 + l * 8;
    *(float4*)&xp[0] = *(float4*)&p[0];
    *(float4*)&xp[4] = *(float4*)&p[4];
  }
}

// ----------------------------------------------------------------- launch ----
extern "C" void kernel_launch(void* const* d_in, const int* in_sizes, int n_in,
                              void* d_out, int out_size, void* d_ws, size_t ws_size,
                              hipStream_t stream) {
  const float* h_prev = (const float*)d_in[0];
  const float* x_l    = (const float*)d_in[1];
  const float* x_ext  = (const float*)d_in[2];
  const float* mw1    = (const float*)d_in[3];
  const float* mb1    = (const float*)d_in[4];
  const float* mw2    = (const float*)d_in[5];
  const float* mb2    = (const float*)d_in[6];
  const float* gw1    = (const float*)d_in[7];
  const float* gb1    = (const float*)d_in[8];
  const float* gw2    = (const float*)d_in[9];
  const float* gb2    = (const float*)d_in[10];
  const float* ln_g   = (const float*)d_in[11];
  const float* ln_b   = (const float*)d_in[12];
  const float* th0    = (const float*)d_in[13];
  float* out = (float*)d_out;

  char* ws = (char*)d_ws;
  float* gates = (float*)ws;                                   // 256 KB
  unsigned short* h1bf = (unsigned short*)(ws + (1u << 18));   // 64 MB
  unsigned short* w2t  = (unsigned short*)(ws + (1u << 18) + (64u << 20));  // 8 MB
  unsigned short* h2bf = (unsigned short*)(ws + (1u << 18) + (72u << 20));  // 64 MB

  hipLaunchKernelGGL(k_gates, dim3(NB / 8), dim3(256), 0, stream,
                     h_prev, gw1, gb1, gw2, gb2, gates);
  hipLaunchKernelGGL(k_h1, dim3(NB * NK * ND / 8 / 256), dim3(256), 0, stream,
                     x_ext, mw1, mb1, h1bf);
  hipLaunchKernelGGL(k_w2t, dim3(8, 8, NK), dim3(256), 0, stream, mw2, w2t);
  hipLaunchKernelGGL(k_gemm, dim3(4, 32, NK), dim3(256), 0, stream,
                     h1bf, w2t, mb2, h2bf);
  hipLaunchKernelGGL(k_final, dim3(NB / 4), dim3(256), 0, stream,
                     h2bf, gates, x_l, ln_g, ln_b, th0, out);
}